// Round 5
// baseline (219.248 us; speedup 1.0000x reference)
//
#include <hip/hip_runtime.h>

#define H 1024
#define BSZ 64
#define TT 512
#define BT (BSZ * TT)   // 32768 rows
#define NSPLIT 4        // N=1024 / BN=256
#define NTILES 16       // K tiles = H / 64

using bf16x8 = __attribute__((ext_vector_type(8))) __bf16;
using f32x4  = __attribute__((ext_vector_type(4))) float;

__device__ __forceinline__ unsigned short f2bf(float f) {
  unsigned u = __float_as_uint(f);
  u += 0x7FFF + ((u >> 16) & 1);   // RTN-even
  return (unsigned short)(u >> 16);
}
__device__ __forceinline__ float bf2f(unsigned short h) {
  return __uint_as_float(((unsigned)h) << 16);
}

#define GLDS(gp, lp) \
  __builtin_amdgcn_global_load_lds( \
      (const __attribute__((address_space(1))) void*)(gp), \
      (__attribute__((address_space(3))) void*)(lp), 16, 0, 0)

// ---------------- Kernel 1: LayerNorm + bf16 cast ----------------
__global__ __launch_bounds__(256) void ln_kernel(
    const float* __restrict__ in, const float* __restrict__ gamma,
    const float* __restrict__ beta, unsigned short* __restrict__ xb) {
  const int row = blockIdx.x;
  const int tid = threadIdx.x;
  const float4 xv = reinterpret_cast<const float4*>(in + (size_t)row * H)[tid];
  float s  = xv.x + xv.y + xv.z + xv.w;
  float ss = xv.x * xv.x + xv.y * xv.y + xv.z * xv.z + xv.w * xv.w;
#pragma unroll
  for (int off = 32; off >= 1; off >>= 1) {
    s  += __shfl_xor(s, off);
    ss += __shfl_xor(ss, off);
  }
  __shared__ float red[2][4];
  const int w = tid >> 6;
  if ((tid & 63) == 0) { red[0][w] = s; red[1][w] = ss; }
  __syncthreads();
  const float tot  = red[0][0] + red[0][1] + red[0][2] + red[0][3];
  const float tot2 = red[1][0] + red[1][1] + red[1][2] + red[1][3];
  const float mu   = tot * (1.0f / H);
  const float var  = tot2 * (1.0f / H) - mu * mu;
  const float rstd = rsqrtf(var + 1e-5f);
  const float4 g  = reinterpret_cast<const float4*>(gamma)[tid];
  const float4 bt = reinterpret_cast<const float4*>(beta)[tid];
  ushort4 o;
  o.x = f2bf((xv.x - mu) * rstd * g.x + bt.x);
  o.y = f2bf((xv.y - mu) * rstd * g.y + bt.y);
  o.z = f2bf((xv.z - mu) * rstd * g.z + bt.z);
  o.w = f2bf((xv.w - mu) * rstd * g.w + bt.w);
  reinterpret_cast<ushort4*>(xb + (size_t)row * H)[tid] = o;
}

// ---------------- Kernel 2: W -> bf16 ----------------
__global__ __launch_bounds__(256) void wcvt_kernel(
    const float* __restrict__ Win, unsigned short* __restrict__ wb) {
  const size_t i = (size_t)blockIdx.x * 1024 + (size_t)threadIdx.x * 4;
  const float4 xv = *reinterpret_cast<const float4*>(Win + i);
  ushort4 o;
  o.x = f2bf(xv.x); o.y = f2bf(xv.y); o.z = f2bf(xv.z); o.w = f2bf(xv.w);
  *reinterpret_cast<ushort4*>(wb + i) = o;
}

// ---------------- Kernel 3: fused scores GEMM (256x256, A-direct) -------
// spart[nt][m] = sum_{d in [nt*256,nt*256+256)} tanh(Wout[m,d]+bW[d])*v[d]
//
// A (X rows) loaded DIRECTLY global->VGPR in MFMA fragment layout
// (lane l: row (l&15)+16*mi, col (l>>4)*8 — 64B-contiguous per 16 lanes,
// L2 absorbs the 4x wn-duplication). Only B (W rows) is LDS-staged
// (dbuf 2x32KB, GLDS width-16, XOR-swizzled). Per K-tile: ONE vmcnt(0)
// (only B(t)'s 4 GLDS in flight, issued a full iter earlier -> no stall)
// + ONE barrier. Write-after-read safe: a wave passes barrier(t) only
// after its iter t-1 MFMAs issued (lgkm-waited) => its ds_reads retired;
// GLDS(t+1) into buf^1 is issued post-barrier.
__global__ __launch_bounds__(512, 2) void score_gemm(
    const unsigned short* __restrict__ xb, const unsigned short* __restrict__ wb,
    const float* __restrict__ bW, const float* __restrict__ v,
    float* __restrict__ spart) {
  // [2 buf][2 kh][256 rows][32 k] bf16 = 64 KiB
  __shared__ unsigned short Bs[32768];
  __shared__ float s_red[4][256];

  const int tid  = threadIdx.x;
  const int w    = tid >> 6, lane = tid & 63;
  const int wm   = w >> 2, wn = w & 3;      // 2 M-waves x 4 N-waves

  // bijective XCD swizzle (512 blocks % 8 == 0)
  const int bid0 = blockIdx.x;
  const int bid  = (bid0 & 7) * 64 + (bid0 >> 3);
  const int mt = bid & 127, nt = bid >> 7;
  const int mbase = mt * 256, nbase = nt * 256;

  // --- B staging geometry (unchanged from R2-R4, verified) ---
  const int srow = lane >> 2;
  const int swz8 = ((lane & 3) ^ ((lane >> 3) & 3)) * 8;       // pre-swizzled src col
  const int ch0 = w, ch1 = 8 + w;
  const unsigned short* gB = wb + (size_t)nbase * H;

  auto stage_B = [&](int tk, int kh, int buf) {
    const int ro   = (buf * 2 + kh) * 8192;
    const int gcol = tk * 64 + kh * 32 + swz8;
    GLDS(gB + (size_t)(ch0 * 16 + srow) * H + gcol, &Bs[ro + ch0 * 512]);
    GLDS(gB + (size_t)(ch1 * 16 + srow) * H + gcol, &Bs[ro + ch1 * 512]);
  };

  // --- B fragment-read geometry (swizzle-matched, unchanged) ---
  const int acoff = (((lane >> 4) ^ (((lane & 15) >> 1) & 3)) * 8);
  const int brow0 = wn * 64 + (lane & 15);

  // --- A direct-load row pointers: frag(mi,kh,t) = aP[mi] + t*64 + kh*32 ---
  const unsigned short* aP[8];
#pragma unroll
  for (int mi = 0; mi < 8; mi++)
    aP[mi] = xb + (size_t)(mbase + wm * 128 + mi * 16 + (lane & 15)) * H
                + ((lane >> 4) * 8);

  f32x4 acc[8][4];
#pragma unroll
  for (int mi = 0; mi < 8; mi++)
#pragma unroll
    for (int ni = 0; ni < 4; ni++) acc[mi][ni] = (f32x4){0.f, 0.f, 0.f, 0.f};

  // prologue: stage B tile0 (both k-halves) into buf0
  stage_B(0, 0, 0);
  stage_B(0, 1, 0);

#pragma unroll
  for (int t = 0; t < NTILES; t++) {
    const int buf = t & 1;
    // drain B(t) GLDS (only thing in flight; issued a full iter ago)
    asm volatile("s_waitcnt vmcnt(0)" ::: "memory");
    __builtin_amdgcn_s_barrier();
    asm volatile("" ::: "memory");
    if (t + 1 < NTILES) {
      stage_B(t + 1, 0, buf ^ 1);
      stage_B(t + 1, 1, buf ^ 1);
    }
#pragma unroll
    for (int kh = 0; kh < 2; kh++) {
      bf16x8 a[8], b[4];
      const int ro = (buf * 2 + kh) * 8192;
#pragma unroll
      for (int mi = 0; mi < 8; mi++)
        a[mi] = *reinterpret_cast<const bf16x8*>(aP[mi] + t * 64 + kh * 32);
#pragma unroll
      for (int ni = 0; ni < 4; ni++)
        b[ni] = *reinterpret_cast<const bf16x8*>(&Bs[ro + (brow0 + ni * 16) * 32 + acoff]);
      __builtin_amdgcn_s_setprio(1);
#pragma unroll
      for (int mi = 0; mi < 8; mi++)
#pragma unroll
        for (int ni = 0; ni < 4; ni++)
          acc[mi][ni] = __builtin_amdgcn_mfma_f32_16x16x32_bf16(a[mi], b[ni], acc[mi][ni], 0, 0, 0);
      __builtin_amdgcn_s_setprio(0);
    }
  }

  // ---- epilogue: tanh(.+bW)*v, reduce over N within block ----
  float sp[8][4];
#pragma unroll
  for (int mi = 0; mi < 8; mi++)
#pragma unroll
    for (int r = 0; r < 4; r++) sp[mi][r] = 0.f;

#pragma unroll
  for (int ni = 0; ni < 4; ni++) {
    const int col = nbase + wn * 64 + ni * 16 + (lane & 15);
    const float bwv = bW[col];
    const float vv  = v[col];
#pragma unroll
    for (int mi = 0; mi < 8; mi++)
#pragma unroll
      for (int r = 0; r < 4; r++) {
        float xv = acc[mi][ni][r] + bwv;
        xv = fminf(fmaxf(xv, -15.f), 15.f);
        const float e = __expf(2.f * xv);
        sp[mi][r] += vv * (e - 1.f) / (e + 1.f);   // tanh
      }
  }
#pragma unroll
  for (int mi = 0; mi < 8; mi++)
#pragma unroll
    for (int r = 0; r < 4; r++) {
      float sv = sp[mi][r];
      sv += __shfl_xor(sv, 1);
      sv += __shfl_xor(sv, 2);
      sv += __shfl_xor(sv, 4);
      sv += __shfl_xor(sv, 8);
      sp[mi][r] = sv;
    }
  if ((lane & 15) == 0) {
#pragma unroll
    for (int mi = 0; mi < 8; mi++)
#pragma unroll
      for (int r = 0; r < 4; r++)
        s_red[wn][wm * 128 + mi * 16 + (lane >> 4) * 4 + r] = sp[mi][r];
  }
  __syncthreads();
  if (tid < 256)
    spart[(size_t)nt * BT + mbase + tid] =
        s_red[0][tid] + s_red[1][tid] + s_red[2][tid] + s_red[3][tid];
}

// ---------------- Kernel 4: softmax over T per batch ----------------
__global__ __launch_bounds__(512) void softmax_kernel(
    const float* __restrict__ spart, const float* __restrict__ bv,
    float* __restrict__ wout) {
  const int b = blockIdx.x, t = threadIdx.x;
  float s = bv[0];
#pragma unroll
  for (int p = 0; p < NSPLIT; p++) s += spart[(size_t)p * BT + b * TT + t];
  if (s != s) s = 0.f;                       // nan_to_num
  s = fminf(fmaxf(s, -10.f), 10.f);          // clip
  float m = s;
#pragma unroll
  for (int off = 32; off >= 1; off >>= 1) m = fmaxf(m, __shfl_xor(m, off));
  __shared__ float redm[8], reds[8];
  const int w = t >> 6;
  if ((t & 63) == 0) redm[w] = m;
  __syncthreads();
  m = redm[0];
#pragma unroll
  for (int i = 1; i < 8; i++) m = fmaxf(m, redm[i]);
  const float e = expf(s - m);
  float su = e;
#pragma unroll
  for (int off = 32; off >= 1; off >>= 1) su += __shfl_xor(su, off);
  if ((t & 63) == 0) reds[w] = su;
  __syncthreads();
  su = 0.f;
#pragma unroll
  for (int i = 0; i < 8; i++) su += reds[i];
  wout[b * TT + t] = e / su;
}

// ---------------- Kernel 5: context partials over t-chunks ----------------
__global__ __launch_bounds__(256) void ctx_part_kernel(
    const unsigned short* __restrict__ xb, const float* __restrict__ wts,
    float* __restrict__ ctxp) {
  const int b = blockIdx.x, c = blockIdx.y, tid = threadIdx.x;
  const int h = tid * 4;
  float a0 = 0.f, a1 = 0.f, a2 = 0.f, a3 = 0.f;
  const unsigned short* xrow = xb + ((size_t)(b * TT + c * 64)) * H + h;
  const float* wrow = wts + b * TT + c * 64;
  for (int t = 0; t < 64; t++) {
    const float wgt = wrow[t];
    const ushort4 xv = *reinterpret_cast<const ushort4*>(xrow + (size_t)t * H);
    a0 += wgt * bf2f(xv.x);
    a1 += wgt * bf2f(xv.y);
    a2 += wgt * bf2f(xv.z);
    a3 += wgt * bf2f(xv.w);
  }
  float4 o = {a0, a1, a2, a3};
  *reinterpret_cast<float4*>(ctxp + ((size_t)c * BSZ + b) * H + h) = o;
}

// ---------------- Kernel 6: context reduce ----------------
__global__ __launch_bounds__(256) void ctx_reduce_kernel(
    const float* __restrict__ ctxp, float* __restrict__ out) {
  const int idx = blockIdx.x * 256 + threadIdx.x;  // 0..65535 = b*H+h
  float s = 0.f;
#pragma unroll
  for (int c = 0; c < 8; c++) s += ctxp[(size_t)c * (BSZ * H) + idx];
  out[idx] = s;
}

extern "C" void kernel_launch(void* const* d_in, const int* in_sizes, int n_in,
                              void* d_out, int out_size, void* d_ws, size_t ws_size,
                              hipStream_t stream) {
  const float* lstm  = (const float*)d_in[0];
  const float* W     = (const float*)d_in[1];
  const float* bW    = (const float*)d_in[2];
  const float* v     = (const float*)d_in[3];
  const float* bv    = (const float*)d_in[4];
  const float* gamma = (const float*)d_in[5];
  const float* beta  = (const float*)d_in[6];
  float* out = (float*)d_out;

  char* ws = (char*)d_ws;
  unsigned short* xb = (unsigned short*)ws;                                   // 64 MiB
  unsigned short* wb = (unsigned short*)(ws + (size_t)BT * H * 2);            // 2 MiB
  float* spart = (float*)(ws + (size_t)BT * H * 2 + (size_t)H * H * 2);       // 512 KiB
  float* ctxp  = (float*)((char*)spart + (size_t)NSPLIT * BT * 4);            // 2 MiB

  float* weights_out = out + BSZ * H;   // context first (65536), then weights (32768)

  ln_kernel<<<BT, 256, 0, stream>>>(lstm, gamma, beta, xb);
  wcvt_kernel<<<(H * H) / 1024, 256, 0, stream>>>(W, wb);
  score_gemm<<<512, 512, 0, stream>>>(xb, wb, bW, v, spart);
  softmax_kernel<<<BSZ, TT, 0, stream>>>(spart, bv, weights_out);
  ctx_part_kernel<<<dim3(BSZ, 8), 256, 0, stream>>>(xb, weights_out, ctxp);
  ctx_reduce_kernel<<<(BSZ * H) / 256, 256, 0, stream>>>(ctxp, out);
}

// Round 6
// 138.742 us; speedup vs baseline: 1.5803x; 1.5803x over previous
//
#include <hip/hip_runtime.h>

#define H 1024
#define BSZ 64
#define TT 512
#define BT (BSZ * TT)   // 32768 rows
#define NSPLIT 4        // N=1024 / BN=256
#define KT 32           // K tiles = H / 32

using bf16x8 = __attribute__((ext_vector_type(8))) __bf16;
using f32x4  = __attribute__((ext_vector_type(4))) float;

__device__ __forceinline__ unsigned short f2bf(float f) {
  unsigned u = __float_as_uint(f);
  u += 0x7FFF + ((u >> 16) & 1);   // RTN-even
  return (unsigned short)(u >> 16);
}
__device__ __forceinline__ float bf2f(unsigned short h) {
  return __uint_as_float(((unsigned)h) << 16);
}

#define GLDS(gp, lp) \
  __builtin_amdgcn_global_load_lds( \
      (const __attribute__((address_space(1))) void*)(gp), \
      (__attribute__((address_space(3))) void*)(lp), 16, 0, 0)

// ---------------- Kernel 1: LayerNorm + bf16 cast ----------------
__global__ __launch_bounds__(256) void ln_kernel(
    const float* __restrict__ in, const float* __restrict__ gamma,
    const float* __restrict__ beta, unsigned short* __restrict__ xb) {
  const int row = blockIdx.x;
  const int tid = threadIdx.x;
  const float4 xv = reinterpret_cast<const float4*>(in + (size_t)row * H)[tid];
  float s  = xv.x + xv.y + xv.z + xv.w;
  float ss = xv.x * xv.x + xv.y * xv.y + xv.z * xv.z + xv.w * xv.w;
#pragma unroll
  for (int off = 32; off >= 1; off >>= 1) {
    s  += __shfl_xor(s, off);
    ss += __shfl_xor(ss, off);
  }
  __shared__ float red[2][4];
  const int w = tid >> 6;
  if ((tid & 63) == 0) { red[0][w] = s; red[1][w] = ss; }
  __syncthreads();
  const float tot  = red[0][0] + red[0][1] + red[0][2] + red[0][3];
  const float tot2 = red[1][0] + red[1][1] + red[1][2] + red[1][3];
  const float mu   = tot * (1.0f / H);
  const float var  = tot2 * (1.0f / H) - mu * mu;
  const float rstd = rsqrtf(var + 1e-5f);
  const float4 g  = reinterpret_cast<const float4*>(gamma)[tid];
  const float4 bt = reinterpret_cast<const float4*>(beta)[tid];
  ushort4 o;
  o.x = f2bf((xv.x - mu) * rstd * g.x + bt.x);
  o.y = f2bf((xv.y - mu) * rstd * g.y + bt.y);
  o.z = f2bf((xv.z - mu) * rstd * g.z + bt.z);
  o.w = f2bf((xv.w - mu) * rstd * g.w + bt.w);
  reinterpret_cast<ushort4*>(xb + (size_t)row * H)[tid] = o;
}

// ---------------- Kernel 2: W -> bf16 ----------------
__global__ __launch_bounds__(256) void wcvt_kernel(
    const float* __restrict__ Win, unsigned short* __restrict__ wb) {
  const size_t i = (size_t)blockIdx.x * 1024 + (size_t)threadIdx.x * 4;
  const float4 xv = *reinterpret_cast<const float4*>(Win + i);
  ushort4 o;
  o.x = f2bf(xv.x); o.y = f2bf(xv.y); o.z = f2bf(xv.z); o.w = f2bf(xv.w);
  *reinterpret_cast<ushort4*>(wb + i) = o;
}

// ---------------- Kernel 3: fused scores GEMM (128x256, 2 blocks/CU) ----
// spart[nt][m] = sum_{d in [nt*256,nt*256+256)} tanh(Wout[m,d]+bW[d])*v[d]
//
// Occupancy-first redesign: wave tile 64x64 (acc=64 regs) so VGPR<=128
// -> 4 waves/SIMD (2 blocks/CU). BK=32, triple-buffered LDS (74 KB),
// prefetch 2 K-tiles ahead with counted vmcnt(3) (never drains mid-loop).
// LDS layout [row][32k] (64B rows); bank swizzle: 16B-slot ^= (row>>1)&3,
// applied on pre-swizzled global source col AND the frag-read slot
// (2 lanes/bank = free). Cross-block wave overlap fills barrier stalls.
__global__ __launch_bounds__(512, 4) void score_gemm(
    const unsigned short* __restrict__ xb, const unsigned short* __restrict__ wb,
    const float* __restrict__ bW, const float* __restrict__ v,
    float* __restrict__ spart) {
  __shared__ unsigned short Abuf[3 * 128 * 32];   // 3 x 8 KB
  __shared__ unsigned short Bbuf[3 * 256 * 32];   // 3 x 16 KB
  __shared__ float s_red[4][128];                 // 2 KB

  const int tid  = threadIdx.x;
  const int w    = tid >> 6, lane = tid & 63;
  const int wm   = w >> 2, wn = w & 3;            // 2 M-waves x 4 N-waves

  // bijective XCD swizzle (1024 blocks % 8 == 0)
  const int bid0 = blockIdx.x;
  const int bid  = (bid0 & 7) * 128 + (bid0 >> 3);
  const int mt = bid & 255, nt = bid >> 8;        // 256 mt x 4 nt
  const int mbase = mt * 128, nbase = nt * 256;

  // --- staging geometry: lane l -> row w*16+(l>>2), colgroup pre-swizzled
  const int srow = lane >> 2;
  const int scol = ((lane & 3) ^ ((lane >> 3) & 3)) * 8;   // bf16 units
  const unsigned short* pA  = xb + (size_t)(mbase + w * 16 + srow) * H + scol;
  const unsigned short* pB0 = wb + (size_t)(nbase + w * 16 + srow) * H + scol;
  const unsigned short* pB1 = wb + (size_t)(nbase + 128 + w * 16 + srow) * H + scol;

  auto stage = [&](int tk, int buf) {   // 3 GLDS / thread (A:1, B:2)
    GLDS(pA  + tk * 32, &Abuf[buf * 4096 + w * 512]);
    GLDS(pB0 + tk * 32, &Bbuf[buf * 8192 + w * 512]);
    GLDS(pB1 + tk * 32, &Bbuf[buf * 8192 + 4096 + w * 512]);
  };

  // --- fragment-read geometry (swizzle-matched) ---
  // slot = (l>>4) ^ ((l>>1)&3); row parts (multiples of 4) don't affect it
  const int slot8 = (((lane >> 4) ^ ((lane >> 1) & 3)) * 8);
  const int a_base = (wm * 64 + (lane & 15)) * 32 + slot8;  // ushort units
  const int b_base = (wn * 64 + (lane & 15)) * 32 + slot8;

  f32x4 acc[4][4];
#pragma unroll
  for (int mi = 0; mi < 4; mi++)
#pragma unroll
    for (int ni = 0; ni < 4; ni++) acc[mi][ni] = (f32x4){0.f, 0.f, 0.f, 0.f};

  // prologue: stage tiles 0,1 into bufs 0,1; tile0 complete before reads
  stage(0, 0);
  stage(1, 1);
  asm volatile("s_waitcnt vmcnt(3)" ::: "memory");
  __builtin_amdgcn_s_barrier();
  asm volatile("" ::: "memory");

  int rb = 0, sb = 2;   // read-buf, stage-buf (uniform -> SGPR)
  for (int t = 0; t < KT; t++) {
    if (t + 2 < KT) {
      stage(t + 2, sb);
      sb = (sb == 2) ? 0 : sb + 1;
    }
    bf16x8 a[4], b[4];
    const int ao = rb * 4096 + a_base;
    const int bo = rb * 8192 + b_base;
#pragma unroll
    for (int mi = 0; mi < 4; mi++)
      a[mi] = *reinterpret_cast<const bf16x8*>(&Abuf[ao + mi * 512]);
#pragma unroll
    for (int ni = 0; ni < 4; ni++)
      b[ni] = *reinterpret_cast<const bf16x8*>(&Bbuf[bo + ni * 512]);
    __builtin_amdgcn_s_setprio(1);
#pragma unroll
    for (int mi = 0; mi < 4; mi++)
#pragma unroll
      for (int ni = 0; ni < 4; ni++)
        acc[mi][ni] = __builtin_amdgcn_mfma_f32_16x16x32_bf16(a[mi], b[ni], acc[mi][ni], 0, 0, 0);
    __builtin_amdgcn_s_setprio(0);
    rb = (rb == 2) ? 0 : rb + 1;
    // tile t+1 must be resident before next iteration's reads:
    // steady state keeps t+2's 3 GLDS in flight (vmcnt(3)); tail drains.
    if (t + 2 < KT)      { asm volatile("s_waitcnt vmcnt(3)" ::: "memory"); }
    else if (t + 1 < KT) { asm volatile("s_waitcnt vmcnt(0)" ::: "memory"); }
    __builtin_amdgcn_s_barrier();
    asm volatile("" ::: "memory");
  }

  // ---- epilogue: tanh(.+bW)*v, reduce over N within block ----
  float sp[4][4];
#pragma unroll
  for (int mi = 0; mi < 4; mi++)
#pragma unroll
    for (int r = 0; r < 4; r++) sp[mi][r] = 0.f;

#pragma unroll
  for (int ni = 0; ni < 4; ni++) {
    const int col = nbase + wn * 64 + ni * 16 + (lane & 15);
    const float bwv = bW[col];
    const float vv  = v[col];
#pragma unroll
    for (int mi = 0; mi < 4; mi++)
#pragma unroll
      for (int r = 0; r < 4; r++) {
        float xv = acc[mi][ni][r] + bwv;
        xv = fminf(fmaxf(xv, -15.f), 15.f);
        const float e = __expf(2.f * xv);
        sp[mi][r] += vv * (e - 1.f) / (e + 1.f);   // tanh
      }
  }
#pragma unroll
  for (int mi = 0; mi < 4; mi++)
#pragma unroll
    for (int r = 0; r < 4; r++) {
      float sv = sp[mi][r];
      sv += __shfl_xor(sv, 1);
      sv += __shfl_xor(sv, 2);
      sv += __shfl_xor(sv, 4);
      sv += __shfl_xor(sv, 8);
      sp[mi][r] = sv;
    }
  if ((lane & 15) == 0) {
#pragma unroll
    for (int mi = 0; mi < 4; mi++)
#pragma unroll
      for (int r = 0; r < 4; r++)
        s_red[wn][wm * 64 + mi * 16 + (lane >> 4) * 4 + r] = sp[mi][r];
  }
  __syncthreads();
  if (tid < 128)
    spart[(size_t)nt * BT + mbase + tid] =
        s_red[0][tid] + s_red[1][tid] + s_red[2][tid] + s_red[3][tid];
}

// ---------------- Kernel 4: softmax over T per batch ----------------
__global__ __launch_bounds__(512) void softmax_kernel(
    const float* __restrict__ spart, const float* __restrict__ bv,
    float* __restrict__ wout) {
  const int b = blockIdx.x, t = threadIdx.x;
  float s = bv[0];
#pragma unroll
  for (int p = 0; p < NSPLIT; p++) s += spart[(size_t)p * BT + b * TT + t];
  if (s != s) s = 0.f;                       // nan_to_num
  s = fminf(fmaxf(s, -10.f), 10.f);          // clip
  float m = s;
#pragma unroll
  for (int off = 32; off >= 1; off >>= 1) m = fmaxf(m, __shfl_xor(m, off));
  __shared__ float redm[8], reds[8];
  const int w = t >> 6;
  if ((t & 63) == 0) redm[w] = m;
  __syncthreads();
  m = redm[0];
#pragma unroll
  for (int i = 1; i < 8; i++) m = fmaxf(m, redm[i]);
  const float e = expf(s - m);
  float su = e;
#pragma unroll
  for (int off = 32; off >= 1; off >>= 1) su += __shfl_xor(su, off);
  if ((t & 63) == 0) reds[w] = su;
  __syncthreads();
  su = 0.f;
#pragma unroll
  for (int i = 0; i < 8; i++) su += reds[i];
  wout[b * TT + t] = e / su;
}

// ---------------- Kernel 5: context partials over t-chunks ----------------
__global__ __launch_bounds__(256) void ctx_part_kernel(
    const unsigned short* __restrict__ xb, const float* __restrict__ wts,
    float* __restrict__ ctxp) {
  const int b = blockIdx.x, c = blockIdx.y, tid = threadIdx.x;
  const int h = tid * 4;
  float a0 = 0.f, a1 = 0.f, a2 = 0.f, a3 = 0.f;
  const unsigned short* xrow = xb + ((size_t)(b * TT + c * 64)) * H + h;
  const float* wrow = wts + b * TT + c * 64;
  for (int t = 0; t < 64; t++) {
    const float wgt = wrow[t];
    const ushort4 xv = *reinterpret_cast<const ushort4*>(xrow + (size_t)t * H);
    a0 += wgt * bf2f(xv.x);
    a1 += wgt * bf2f(xv.y);
    a2 += wgt * bf2f(xv.z);
    a3 += wgt * bf2f(xv.w);
  }
  float4 o = {a0, a1, a2, a3};
  *reinterpret_cast<float4*>(ctxp + ((size_t)c * BSZ + b) * H + h) = o;
}

// ---------------- Kernel 6: context reduce ----------------
__global__ __launch_bounds__(256) void ctx_reduce_kernel(
    const float* __restrict__ ctxp, float* __restrict__ out) {
  const int idx = blockIdx.x * 256 + threadIdx.x;  // 0..65535 = b*H+h
  float s = 0.f;
#pragma unroll
  for (int c = 0; c < 8; c++) s += ctxp[(size_t)c * (BSZ * H) + idx];
  out[idx] = s;
}

extern "C" void kernel_launch(void* const* d_in, const int* in_sizes, int n_in,
                              void* d_out, int out_size, void* d_ws, size_t ws_size,
                              hipStream_t stream) {
  const float* lstm  = (const float*)d_in[0];
  const float* W     = (const float*)d_in[1];
  const float* bW    = (const float*)d_in[2];
  const float* v     = (const float*)d_in[3];
  const float* bv    = (const float*)d_in[4];
  const float* gamma = (const float*)d_in[5];
  const float* beta  = (const float*)d_in[6];
  float* out = (float*)d_out;

  char* ws = (char*)d_ws;
  unsigned short* xb = (unsigned short*)ws;                                   // 64 MiB
  unsigned short* wb = (unsigned short*)(ws + (size_t)BT * H * 2);            // 2 MiB
  float* spart = (float*)(ws + (size_t)BT * H * 2 + (size_t)H * H * 2);       // 512 KiB
  float* ctxp  = (float*)((char*)spart + (size_t)NSPLIT * BT * 4);            // 2 MiB

  float* weights_out = out + BSZ * H;   // context first (65536), then weights (32768)

  ln_kernel<<<BT, 256, 0, stream>>>(lstm, gamma, beta, xb);
  wcvt_kernel<<<(H * H) / 1024, 256, 0, stream>>>(W, wb);
  score_gemm<<<1024, 512, 0, stream>>>(xb, wb, bW, v, spart);
  softmax_kernel<<<BSZ, TT, 0, stream>>>(spart, bv, weights_out);
  ctx_part_kernel<<<dim3(BSZ, 8), 256, 0, stream>>>(xb, weights_out, ctxp);
  ctx_reduce_kernel<<<(BSZ * H) / 256, 256, 0, stream>>>(ctxp, out);
}

// Round 7
// 138.358 us; speedup vs baseline: 1.5846x; 1.0028x over previous
//
#include <hip/hip_runtime.h>

#define H 1024
#define BSZ 64
#define TT 512
#define BT (BSZ * TT)   // 32768 rows
#define NSPLIT 4        // N=1024 / BN=256
#define KT 32           // K tiles = H / 32

using bf16x8 = __attribute__((ext_vector_type(8))) __bf16;
using f32x4  = __attribute__((ext_vector_type(4))) float;

__device__ __forceinline__ unsigned short f2bf(float f) {
  unsigned u = __float_as_uint(f);
  u += 0x7FFF + ((u >> 16) & 1);   // RTN-even
  return (unsigned short)(u >> 16);
}
__device__ __forceinline__ float bf2f(unsigned short h) {
  return __uint_as_float(((unsigned)h) << 16);
}

#define GLDS(gp, lp) \
  __builtin_amdgcn_global_load_lds( \
      (const __attribute__((address_space(1))) void*)(gp), \
      (__attribute__((address_space(3))) void*)(lp), 16, 0, 0)

// ---------------- Kernel 1: LayerNorm + bf16 cast ----------------
__global__ __launch_bounds__(256) void ln_kernel(
    const float* __restrict__ in, const float* __restrict__ gamma,
    const float* __restrict__ beta, unsigned short* __restrict__ xb) {
  const int row = blockIdx.x;
  const int tid = threadIdx.x;
  const float4 xv = reinterpret_cast<const float4*>(in + (size_t)row * H)[tid];
  float s  = xv.x + xv.y + xv.z + xv.w;
  float ss = xv.x * xv.x + xv.y * xv.y + xv.z * xv.z + xv.w * xv.w;
#pragma unroll
  for (int off = 32; off >= 1; off >>= 1) {
    s  += __shfl_xor(s, off);
    ss += __shfl_xor(ss, off);
  }
  __shared__ float red[2][4];
  const int w = tid >> 6;
  if ((tid & 63) == 0) { red[0][w] = s; red[1][w] = ss; }
  __syncthreads();
  const float tot  = red[0][0] + red[0][1] + red[0][2] + red[0][3];
  const float tot2 = red[1][0] + red[1][1] + red[1][2] + red[1][3];
  const float mu   = tot * (1.0f / H);
  const float var  = tot2 * (1.0f / H) - mu * mu;
  const float rstd = rsqrtf(var + 1e-5f);
  const float4 g  = reinterpret_cast<const float4*>(gamma)[tid];
  const float4 bt = reinterpret_cast<const float4*>(beta)[tid];
  ushort4 o;
  o.x = f2bf((xv.x - mu) * rstd * g.x + bt.x);
  o.y = f2bf((xv.y - mu) * rstd * g.y + bt.y);
  o.z = f2bf((xv.z - mu) * rstd * g.z + bt.z);
  o.w = f2bf((xv.w - mu) * rstd * g.w + bt.w);
  reinterpret_cast<ushort4*>(xb + (size_t)row * H)[tid] = o;
}

// ---------------- Kernel 2: W -> bf16 ----------------
__global__ __launch_bounds__(256) void wcvt_kernel(
    const float* __restrict__ Win, unsigned short* __restrict__ wb) {
  const size_t i = (size_t)blockIdx.x * 1024 + (size_t)threadIdx.x * 4;
  const float4 xv = *reinterpret_cast<const float4*>(Win + i);
  ushort4 o;
  o.x = f2bf(xv.x); o.y = f2bf(xv.y); o.z = f2bf(xv.z); o.w = f2bf(xv.w);
  *reinterpret_cast<ushort4*>(wb + i) = o;
}

// ---------------- Kernel 3: fused scores GEMM (128x256, 2 blocks/CU) ----
// spart[nt][m] = sum_{d in [nt*256,nt*256+256)} tanh(Wout[m,d]+bW[d])*v[d]
//
// Occupancy-first redesign: wave tile 64x64 (acc=64 regs) so VGPR<=128
// -> 4 waves/SIMD (2 blocks/CU). BK=32, triple-buffered LDS (74 KB),
// prefetch 2 K-tiles ahead with counted vmcnt(3) (never drains mid-loop).
// LDS layout [row][32k] (64B rows); bank swizzle: 16B-slot ^= (row>>1)&3,
// applied on pre-swizzled global source col AND the frag-read slot
// (2 lanes/bank = free). Cross-block wave overlap fills barrier stalls.
__global__ __launch_bounds__(512, 4) void score_gemm(
    const unsigned short* __restrict__ xb, const unsigned short* __restrict__ wb,
    const float* __restrict__ bW, const float* __restrict__ v,
    float* __restrict__ spart) {
  __shared__ unsigned short Abuf[3 * 128 * 32];   // 3 x 8 KB
  __shared__ unsigned short Bbuf[3 * 256 * 32];   // 3 x 16 KB
  __shared__ float s_red[4][128];                 // 2 KB

  const int tid  = threadIdx.x;
  const int w    = tid >> 6, lane = tid & 63;
  const int wm   = w >> 2, wn = w & 3;            // 2 M-waves x 4 N-waves

  // bijective XCD swizzle (1024 blocks % 8 == 0)
  const int bid0 = blockIdx.x;
  const int bid  = (bid0 & 7) * 128 + (bid0 >> 3);
  const int mt = bid & 255, nt = bid >> 8;        // 256 mt x 4 nt
  const int mbase = mt * 128, nbase = nt * 256;

  // --- staging geometry: lane l -> row w*16+(l>>2), colgroup pre-swizzled
  const int srow = lane >> 2;
  const int scol = ((lane & 3) ^ ((lane >> 3) & 3)) * 8;   // bf16 units
  const unsigned short* pA  = xb + (size_t)(mbase + w * 16 + srow) * H + scol;
  const unsigned short* pB0 = wb + (size_t)(nbase + w * 16 + srow) * H + scol;
  const unsigned short* pB1 = wb + (size_t)(nbase + 128 + w * 16 + srow) * H + scol;

  auto stage = [&](int tk, int buf) {   // 3 GLDS / thread (A:1, B:2)
    GLDS(pA  + tk * 32, &Abuf[buf * 4096 + w * 512]);
    GLDS(pB0 + tk * 32, &Bbuf[buf * 8192 + w * 512]);
    GLDS(pB1 + tk * 32, &Bbuf[buf * 8192 + 4096 + w * 512]);
  };

  // --- fragment-read geometry (swizzle-matched) ---
  // slot = (l>>4) ^ ((l>>1)&3); row parts (multiples of 4) don't affect it
  const int slot8 = (((lane >> 4) ^ ((lane >> 1) & 3)) * 8);
  const int a_base = (wm * 64 + (lane & 15)) * 32 + slot8;  // ushort units
  const int b_base = (wn * 64 + (lane & 15)) * 32 + slot8;

  f32x4 acc[4][4];
#pragma unroll
  for (int mi = 0; mi < 4; mi++)
#pragma unroll
    for (int ni = 0; ni < 4; ni++) acc[mi][ni] = (f32x4){0.f, 0.f, 0.f, 0.f};

  // prologue: stage tiles 0,1 into bufs 0,1; tile0 complete before reads
  stage(0, 0);
  stage(1, 1);
  asm volatile("s_waitcnt vmcnt(3)" ::: "memory");
  __builtin_amdgcn_s_barrier();
  asm volatile("" ::: "memory");

  int rb = 0, sb = 2;   // read-buf, stage-buf (uniform -> SGPR)
  for (int t = 0; t < KT; t++) {
    if (t + 2 < KT) {
      stage(t + 2, sb);
      sb = (sb == 2) ? 0 : sb + 1;
    }
    bf16x8 a[4], b[4];
    const int ao = rb * 4096 + a_base;
    const int bo = rb * 8192 + b_base;
#pragma unroll
    for (int mi = 0; mi < 4; mi++)
      a[mi] = *reinterpret_cast<const bf16x8*>(&Abuf[ao + mi * 512]);
#pragma unroll
    for (int ni = 0; ni < 4; ni++)
      b[ni] = *reinterpret_cast<const bf16x8*>(&Bbuf[bo + ni * 512]);
    __builtin_amdgcn_s_setprio(1);
#pragma unroll
    for (int mi = 0; mi < 4; mi++)
#pragma unroll
      for (int ni = 0; ni < 4; ni++)
        acc[mi][ni] = __builtin_amdgcn_mfma_f32_16x16x32_bf16(a[mi], b[ni], acc[mi][ni], 0, 0, 0);
    __builtin_amdgcn_s_setprio(0);
    rb = (rb == 2) ? 0 : rb + 1;
    // tile t+1 must be resident before next iteration's reads:
    // steady state keeps t+2's 3 GLDS in flight (vmcnt(3)); tail drains.
    if (t + 2 < KT)      { asm volatile("s_waitcnt vmcnt(3)" ::: "memory"); }
    else if (t + 1 < KT) { asm volatile("s_waitcnt vmcnt(0)" ::: "memory"); }
    __builtin_amdgcn_s_barrier();
    asm volatile("" ::: "memory");
  }

  // ---- epilogue: tanh(.+bW)*v, reduce over N within block ----
  float sp[4][4];
#pragma unroll
  for (int mi = 0; mi < 4; mi++)
#pragma unroll
    for (int r = 0; r < 4; r++) sp[mi][r] = 0.f;

#pragma unroll
  for (int ni = 0; ni < 4; ni++) {
    const int col = nbase + wn * 64 + ni * 16 + (lane & 15);
    const float bwv = bW[col];
    const float vv  = v[col];
#pragma unroll
    for (int mi = 0; mi < 4; mi++)
#pragma unroll
      for (int r = 0; r < 4; r++) {
        float xv = acc[mi][ni][r] + bwv;
        xv = fminf(fmaxf(xv, -15.f), 15.f);
        const float e = __expf(2.f * xv);
        sp[mi][r] += vv * (e - 1.f) / (e + 1.f);   // tanh
      }
  }
#pragma unroll
  for (int mi = 0; mi < 4; mi++)
#pragma unroll
    for (int r = 0; r < 4; r++) {
      float sv = sp[mi][r];
      sv += __shfl_xor(sv, 1);
      sv += __shfl_xor(sv, 2);
      sv += __shfl_xor(sv, 4);
      sv += __shfl_xor(sv, 8);
      sp[mi][r] = sv;
    }
  if ((lane & 15) == 0) {
#pragma unroll
    for (int mi = 0; mi < 4; mi++)
#pragma unroll
      for (int r = 0; r < 4; r++)
        s_red[wn][wm * 64 + mi * 16 + (lane >> 4) * 4 + r] = sp[mi][r];
  }
  __syncthreads();
  if (tid < 128)
    spart[(size_t)nt * BT + mbase + tid] =
        s_red[0][tid] + s_red[1][tid] + s_red[2][tid] + s_red[3][tid];
}

// ---------------- Kernel 4: softmax over T per batch ----------------
__global__ __launch_bounds__(512) void softmax_kernel(
    const float* __restrict__ spart, const float* __restrict__ bv,
    float* __restrict__ wout) {
  const int b = blockIdx.x, t = threadIdx.x;
  float s = bv[0];
#pragma unroll
  for (int p = 0; p < NSPLIT; p++) s += spart[(size_t)p * BT + b * TT + t];
  if (s != s) s = 0.f;                       // nan_to_num
  s = fminf(fmaxf(s, -10.f), 10.f);          // clip
  float m = s;
#pragma unroll
  for (int off = 32; off >= 1; off >>= 1) m = fmaxf(m, __shfl_xor(m, off));
  __shared__ float redm[8], reds[8];
  const int w = t >> 6;
  if ((t & 63) == 0) redm[w] = m;
  __syncthreads();
  m = redm[0];
#pragma unroll
  for (int i = 1; i < 8; i++) m = fmaxf(m, redm[i]);
  const float e = expf(s - m);
  float su = e;
#pragma unroll
  for (int off = 32; off >= 1; off >>= 1) su += __shfl_xor(su, off);
  if ((t & 63) == 0) reds[w] = su;
  __syncthreads();
  su = 0.f;
#pragma unroll
  for (int i = 0; i < 8; i++) su += reds[i];
  wout[b * TT + t] = e / su;
}

// ---------------- Kernel 5: context partials over t-chunks ----------------
__global__ __launch_bounds__(256) void ctx_part_kernel(
    const unsigned short* __restrict__ xb, const float* __restrict__ wts,
    float* __restrict__ ctxp) {
  const int b = blockIdx.x, c = blockIdx.y, tid = threadIdx.x;
  const int h = tid * 4;
  float a0 = 0.f, a1 = 0.f, a2 = 0.f, a3 = 0.f;
  const unsigned short* xrow = xb + ((size_t)(b * TT + c * 64)) * H + h;
  const float* wrow = wts + b * TT + c * 64;
  for (int t = 0; t < 64; t++) {
    const float wgt = wrow[t];
    const ushort4 xv = *reinterpret_cast<const ushort4*>(xrow + (size_t)t * H);
    a0 += wgt * bf2f(xv.x);
    a1 += wgt * bf2f(xv.y);
    a2 += wgt * bf2f(xv.z);
    a3 += wgt * bf2f(xv.w);
  }
  float4 o = {a0, a1, a2, a3};
  *reinterpret_cast<float4*>(ctxp + ((size_t)c * BSZ + b) * H + h) = o;
}

// ---------------- Kernel 6: context reduce ----------------
__global__ __launch_bounds__(256) void ctx_reduce_kernel(
    const float* __restrict__ ctxp, float* __restrict__ out) {
  const int idx = blockIdx.x * 256 + threadIdx.x;  // 0..65535 = b*H+h
  float s = 0.f;
#pragma unroll
  for (int c = 0; c < 8; c++) s += ctxp[(size_t)c * (BSZ * H) + idx];
  out[idx] = s;
}

extern "C" void kernel_launch(void* const* d_in, const int* in_sizes, int n_in,
                              void* d_out, int out_size, void* d_ws, size_t ws_size,
                              hipStream_t stream) {
  const float* lstm  = (const float*)d_in[0];
  const float* W     = (const float*)d_in[1];
  const float* bW    = (const float*)d_in[2];
  const float* v     = (const float*)d_in[3];
  const float* bv    = (const float*)d_in[4];
  const float* gamma = (const float*)d_in[5];
  const float* beta  = (const float*)d_in[6];
  float* out = (float*)d_out;

  char* ws = (char*)d_ws;
  unsigned short* xb = (unsigned short*)ws;                                   // 64 MiB
  unsigned short* wb = (unsigned short*)(ws + (size_t)BT * H * 2);            // 2 MiB
  float* spart = (float*)(ws + (size_t)BT * H * 2 + (size_t)H * H * 2);       // 512 KiB
  float* ctxp  = (float*)((char*)spart + (size_t)NSPLIT * BT * 4);            // 2 MiB

  float* weights_out = out + BSZ * H;   // context first (65536), then weights (32768)

  ln_kernel<<<BT, 256, 0, stream>>>(lstm, gamma, beta, xb);
  wcvt_kernel<<<(H * H) / 1024, 256, 0, stream>>>(W, wb);
  score_gemm<<<1024, 512, 0, stream>>>(xb, wb, bW, v, spart);
  softmax_kernel<<<BSZ, TT, 0, stream>>>(spart, bv, weights_out);
  ctx_part_kernel<<<dim3(BSZ, 8), 256, 0, stream>>>(xb, weights_out, ctxp);
  ctx_reduce_kernel<<<(BSZ * H) / 256, 256, 0, stream>>>(ctxp, out);
}

// Round 8
// 138.177 us; speedup vs baseline: 1.5867x; 1.0013x over previous
//
#include <hip/hip_runtime.h>

#define H 1024
#define BSZ 64
#define TT 512
#define BT (BSZ * TT)   // 32768 rows
#define NSPLIT 4        // N=1024 / BN=256
#define KT 32           // K tiles = H / 32

using bf16x8 = __attribute__((ext_vector_type(8))) __bf16;
using f32x4  = __attribute__((ext_vector_type(4))) float;

__device__ __forceinline__ unsigned short f2bf(float f) {
  unsigned u = __float_as_uint(f);
  u += 0x7FFF + ((u >> 16) & 1);   // RTN-even
  return (unsigned short)(u >> 16);
}
__device__ __forceinline__ float bf2f(unsigned short h) {
  return __uint_as_float(((unsigned)h) << 16);
}

#define GLDS(gp, lp) \
  __builtin_amdgcn_global_load_lds( \
      (const __attribute__((address_space(1))) void*)(gp), \
      (__attribute__((address_space(3))) void*)(lp), 16, 0, 0)

// ---------------- Kernel 1: LayerNorm + bf16 cast ----------------
__global__ __launch_bounds__(256) void ln_kernel(
    const float* __restrict__ in, const float* __restrict__ gamma,
    const float* __restrict__ beta, unsigned short* __restrict__ xb) {
  const int row = blockIdx.x;
  const int tid = threadIdx.x;
  const float4 xv = reinterpret_cast<const float4*>(in + (size_t)row * H)[tid];
  float s  = xv.x + xv.y + xv.z + xv.w;
  float ss = xv.x * xv.x + xv.y * xv.y + xv.z * xv.z + xv.w * xv.w;
#pragma unroll
  for (int off = 32; off >= 1; off >>= 1) {
    s  += __shfl_xor(s, off);
    ss += __shfl_xor(ss, off);
  }
  __shared__ float red[2][4];
  const int w = tid >> 6;
  if ((tid & 63) == 0) { red[0][w] = s; red[1][w] = ss; }
  __syncthreads();
  const float tot  = red[0][0] + red[0][1] + red[0][2] + red[0][3];
  const float tot2 = red[1][0] + red[1][1] + red[1][2] + red[1][3];
  const float mu   = tot * (1.0f / H);
  const float var  = tot2 * (1.0f / H) - mu * mu;
  const float rstd = rsqrtf(var + 1e-5f);
  const float4 g  = reinterpret_cast<const float4*>(gamma)[tid];
  const float4 bt = reinterpret_cast<const float4*>(beta)[tid];
  ushort4 o;
  o.x = f2bf((xv.x - mu) * rstd * g.x + bt.x);
  o.y = f2bf((xv.y - mu) * rstd * g.y + bt.y);
  o.z = f2bf((xv.z - mu) * rstd * g.z + bt.z);
  o.w = f2bf((xv.w - mu) * rstd * g.w + bt.w);
  reinterpret_cast<ushort4*>(xb + (size_t)row * H)[tid] = o;
}

// ---------------- Kernel 2: W -> bf16 ----------------
__global__ __launch_bounds__(256) void wcvt_kernel(
    const float* __restrict__ Win, unsigned short* __restrict__ wb) {
  const size_t i = (size_t)blockIdx.x * 1024 + (size_t)threadIdx.x * 4;
  const float4 xv = *reinterpret_cast<const float4*>(Win + i);
  ushort4 o;
  o.x = f2bf(xv.x); o.y = f2bf(xv.y); o.z = f2bf(xv.z); o.w = f2bf(xv.w);
  *reinterpret_cast<ushort4*>(wb + i) = o;
}

// ---------------- Kernel 3: fused scores GEMM (128x256, 2 blocks/CU) ----
// spart[nt][m] = sum_{d in [nt*256,nt*256+256)} tanh(Wout[m,d]+bW[d])*v[d]
//
// Occupancy-first redesign: wave tile 64x64 (acc=64 regs) so VGPR<=128
// -> 4 waves/SIMD (2 blocks/CU). BK=32, triple-buffered LDS (74 KB),
// prefetch 2 K-tiles ahead with counted vmcnt(3) (never drains mid-loop).
// LDS layout [row][32k] (64B rows); bank swizzle: 16B-slot ^= (row>>1)&3,
// applied on pre-swizzled global source col AND the frag-read slot
// (2 lanes/bank = free). Cross-block wave overlap fills barrier stalls.
__global__ __launch_bounds__(512, 4) void score_gemm(
    const unsigned short* __restrict__ xb, const unsigned short* __restrict__ wb,
    const float* __restrict__ bW, const float* __restrict__ v,
    float* __restrict__ spart) {
  __shared__ unsigned short Abuf[3 * 128 * 32];   // 3 x 8 KB
  __shared__ unsigned short Bbuf[3 * 256 * 32];   // 3 x 16 KB
  __shared__ float s_red[4][128];                 // 2 KB

  const int tid  = threadIdx.x;
  const int w    = tid >> 6, lane = tid & 63;
  const int wm   = w >> 2, wn = w & 3;            // 2 M-waves x 4 N-waves

  // bijective XCD swizzle (1024 blocks % 8 == 0)
  const int bid0 = blockIdx.x;
  const int bid  = (bid0 & 7) * 128 + (bid0 >> 3);
  const int mt = bid & 255, nt = bid >> 8;        // 256 mt x 4 nt
  const int mbase = mt * 128, nbase = nt * 256;

  // --- staging geometry: lane l -> row w*16+(l>>2), colgroup pre-swizzled
  const int srow = lane >> 2;
  const int scol = ((lane & 3) ^ ((lane >> 3) & 3)) * 8;   // bf16 units
  const unsigned short* pA  = xb + (size_t)(mbase + w * 16 + srow) * H + scol;
  const unsigned short* pB0 = wb + (size_t)(nbase + w * 16 + srow) * H + scol;
  const unsigned short* pB1 = wb + (size_t)(nbase + 128 + w * 16 + srow) * H + scol;

  auto stage = [&](int tk, int buf) {   // 3 GLDS / thread (A:1, B:2)
    GLDS(pA  + tk * 32, &Abuf[buf * 4096 + w * 512]);
    GLDS(pB0 + tk * 32, &Bbuf[buf * 8192 + w * 512]);
    GLDS(pB1 + tk * 32, &Bbuf[buf * 8192 + 4096 + w * 512]);
  };

  // --- fragment-read geometry (swizzle-matched) ---
  // slot = (l>>4) ^ ((l>>1)&3); row parts (multiples of 4) don't affect it
  const int slot8 = (((lane >> 4) ^ ((lane >> 1) & 3)) * 8);
  const int a_base = (wm * 64 + (lane & 15)) * 32 + slot8;  // ushort units
  const int b_base = (wn * 64 + (lane & 15)) * 32 + slot8;

  f32x4 acc[4][4];
#pragma unroll
  for (int mi = 0; mi < 4; mi++)
#pragma unroll
    for (int ni = 0; ni < 4; ni++) acc[mi][ni] = (f32x4){0.f, 0.f, 0.f, 0.f};

  // prologue: stage tiles 0,1 into bufs 0,1; tile0 complete before reads
  stage(0, 0);
  stage(1, 1);
  asm volatile("s_waitcnt vmcnt(3)" ::: "memory");
  __builtin_amdgcn_s_barrier();
  asm volatile("" ::: "memory");

  int rb = 0, sb = 2;   // read-buf, stage-buf (uniform -> SGPR)
  for (int t = 0; t < KT; t++) {
    if (t + 2 < KT) {
      stage(t + 2, sb);
      sb = (sb == 2) ? 0 : sb + 1;
    }
    bf16x8 a[4], b[4];
    const int ao = rb * 4096 + a_base;
    const int bo = rb * 8192 + b_base;
#pragma unroll
    for (int mi = 0; mi < 4; mi++)
      a[mi] = *reinterpret_cast<const bf16x8*>(&Abuf[ao + mi * 512]);
#pragma unroll
    for (int ni = 0; ni < 4; ni++)
      b[ni] = *reinterpret_cast<const bf16x8*>(&Bbuf[bo + ni * 512]);
    __builtin_amdgcn_s_setprio(1);
#pragma unroll
    for (int mi = 0; mi < 4; mi++)
#pragma unroll
      for (int ni = 0; ni < 4; ni++)
        acc[mi][ni] = __builtin_amdgcn_mfma_f32_16x16x32_bf16(a[mi], b[ni], acc[mi][ni], 0, 0, 0);
    __builtin_amdgcn_s_setprio(0);
    rb = (rb == 2) ? 0 : rb + 1;
    // tile t+1 must be resident before next iteration's reads:
    // steady state keeps t+2's 3 GLDS in flight (vmcnt(3)); tail drains.
    if (t + 2 < KT)      { asm volatile("s_waitcnt vmcnt(3)" ::: "memory"); }
    else if (t + 1 < KT) { asm volatile("s_waitcnt vmcnt(0)" ::: "memory"); }
    __builtin_amdgcn_s_barrier();
    asm volatile("" ::: "memory");
  }

  // ---- epilogue: tanh(.+bW)*v, reduce over N within block ----
  float sp[4][4];
#pragma unroll
  for (int mi = 0; mi < 4; mi++)
#pragma unroll
    for (int r = 0; r < 4; r++) sp[mi][r] = 0.f;

#pragma unroll
  for (int ni = 0; ni < 4; ni++) {
    const int col = nbase + wn * 64 + ni * 16 + (lane & 15);
    const float bwv = bW[col];
    const float vv  = v[col];
#pragma unroll
    for (int mi = 0; mi < 4; mi++)
#pragma unroll
      for (int r = 0; r < 4; r++) {
        float xv = acc[mi][ni][r] + bwv;
        xv = fminf(fmaxf(xv, -15.f), 15.f);
        const float e = __expf(2.f * xv);
        sp[mi][r] += vv * (e - 1.f) / (e + 1.f);   // tanh
      }
  }
#pragma unroll
  for (int mi = 0; mi < 4; mi++)
#pragma unroll
    for (int r = 0; r < 4; r++) {
      float sv = sp[mi][r];
      sv += __shfl_xor(sv, 1);
      sv += __shfl_xor(sv, 2);
      sv += __shfl_xor(sv, 4);
      sv += __shfl_xor(sv, 8);
      sp[mi][r] = sv;
    }
  if ((lane & 15) == 0) {
#pragma unroll
    for (int mi = 0; mi < 4; mi++)
#pragma unroll
      for (int r = 0; r < 4; r++)
        s_red[wn][wm * 64 + mi * 16 + (lane >> 4) * 4 + r] = sp[mi][r];
  }
  __syncthreads();
  if (tid < 128)
    spart[(size_t)nt * BT + mbase + tid] =
        s_red[0][tid] + s_red[1][tid] + s_red[2][tid] + s_red[3][tid];
}

// ---------------- Kernel 4: softmax over T per batch ----------------
__global__ __launch_bounds__(512) void softmax_kernel(
    const float* __restrict__ spart, const float* __restrict__ bv,
    float* __restrict__ wout) {
  const int b = blockIdx.x, t = threadIdx.x;
  float s = bv[0];
#pragma unroll
  for (int p = 0; p < NSPLIT; p++) s += spart[(size_t)p * BT + b * TT + t];
  if (s != s) s = 0.f;                       // nan_to_num
  s = fminf(fmaxf(s, -10.f), 10.f);          // clip
  float m = s;
#pragma unroll
  for (int off = 32; off >= 1; off >>= 1) m = fmaxf(m, __shfl_xor(m, off));
  __shared__ float redm[8], reds[8];
  const int w = t >> 6;
  if ((t & 63) == 0) redm[w] = m;
  __syncthreads();
  m = redm[0];
#pragma unroll
  for (int i = 1; i < 8; i++) m = fmaxf(m, redm[i]);
  const float e = expf(s - m);
  float su = e;
#pragma unroll
  for (int off = 32; off >= 1; off >>= 1) su += __shfl_xor(su, off);
  if ((t & 63) == 0) reds[w] = su;
  __syncthreads();
  su = 0.f;
#pragma unroll
  for (int i = 0; i < 8; i++) su += reds[i];
  wout[b * TT + t] = e / su;
}

// ---------------- Kernel 5: context partials over t-chunks ----------------
__global__ __launch_bounds__(256) void ctx_part_kernel(
    const unsigned short* __restrict__ xb, const float* __restrict__ wts,
    float* __restrict__ ctxp) {
  const int b = blockIdx.x, c = blockIdx.y, tid = threadIdx.x;
  const int h = tid * 4;
  float a0 = 0.f, a1 = 0.f, a2 = 0.f, a3 = 0.f;
  const unsigned short* xrow = xb + ((size_t)(b * TT + c * 64)) * H + h;
  const float* wrow = wts + b * TT + c * 64;
  for (int t = 0; t < 64; t++) {
    const float wgt = wrow[t];
    const ushort4 xv = *reinterpret_cast<const ushort4*>(xrow + (size_t)t * H);
    a0 += wgt * bf2f(xv.x);
    a1 += wgt * bf2f(xv.y);
    a2 += wgt * bf2f(xv.z);
    a3 += wgt * bf2f(xv.w);
  }
  float4 o = {a0, a1, a2, a3};
  *reinterpret_cast<float4*>(ctxp + ((size_t)c * BSZ + b) * H + h) = o;
}

// ---------------- Kernel 6: context reduce ----------------
__global__ __launch_bounds__(256) void ctx_reduce_kernel(
    const float* __restrict__ ctxp, float* __restrict__ out) {
  const int idx = blockIdx.x * 256 + threadIdx.x;  // 0..65535 = b*H+h
  float s = 0.f;
#pragma unroll
  for (int c = 0; c < 8; c++) s += ctxp[(size_t)c * (BSZ * H) + idx];
  out[idx] = s;
}

extern "C" void kernel_launch(void* const* d_in, const int* in_sizes, int n_in,
                              void* d_out, int out_size, void* d_ws, size_t ws_size,
                              hipStream_t stream) {
  const float* lstm  = (const float*)d_in[0];
  const float* W     = (const float*)d_in[1];
  const float* bW    = (const float*)d_in[2];
  const float* v     = (const float*)d_in[3];
  const float* bv    = (const float*)d_in[4];
  const float* gamma = (const float*)d_in[5];
  const float* beta  = (const float*)d_in[6];
  float* out = (float*)d_out;

  char* ws = (char*)d_ws;
  unsigned short* xb = (unsigned short*)ws;                                   // 64 MiB
  unsigned short* wb = (unsigned short*)(ws + (size_t)BT * H * 2);            // 2 MiB
  float* spart = (float*)(ws + (size_t)BT * H * 2 + (size_t)H * H * 2);       // 512 KiB
  float* ctxp  = (float*)((char*)spart + (size_t)NSPLIT * BT * 4);            // 2 MiB

  float* weights_out = out + BSZ * H;   // context first (65536), then weights (32768)

  ln_kernel<<<BT, 256, 0, stream>>>(lstm, gamma, beta, xb);
  wcvt_kernel<<<(H * H) / 1024, 256, 0, stream>>>(W, wb);
  score_gemm<<<1024, 512, 0, stream>>>(xb, wb, bW, v, spart);
  softmax_kernel<<<BSZ, TT, 0, stream>>>(spart, bv, weights_out);
  ctx_part_kernel<<<dim3(BSZ, 8), 256, 0, stream>>>(xb, weights_out, ctxp);
  ctx_reduce_kernel<<<(BSZ * H) / 256, 256, 0, stream>>>(ctxp, out);
}